// Round 4
// baseline (176.135 us; speedup 1.0000x reference)
//
#include <hip/hip_runtime.h>

typedef __bf16 bf16;
typedef bf16 bf16x8 __attribute__((ext_vector_type(8)));
typedef float f32x4 __attribute__((ext_vector_type(4)));

#define NB    128
#define NTOK  2048
#define INDIM 256
#define HIDW  128
#define NEXP  8
#define NMODE 4
#define KC    256
#define DC    64
#define NSYM  4096

#define RLN2_4 5.770780163555853f    // 4/ln2
#define RLN2_2 2.8853900817779268f   // 2/ln2
#define NLN2_8 0.0866433975699932f   // ln2/8

// ---------------- Router: LN -> GELU MLP -> expert argmax + power scale (f64, parallel dots) ----
__global__ __launch_bounds__(256)
void router_kernel(const float* __restrict__ phi,
                   const float* __restrict__ ln_g, const float* __restrict__ ln_b,
                   const float* __restrict__ W1, const float* __restrict__ b1,
                   const float* __restrict__ W2, const float* __restrict__ b2,
                   const float* __restrict__ We, const float* __restrict__ be,
                   const float* __restrict__ Wm, const float* __restrict__ bm,
                   float* __restrict__ scale_out, int* __restrict__ eidx_out)
{
  const int b = blockIdx.x, t = threadIdx.x;
  __shared__ double xs[INDIM];
  __shared__ double hs[HIDW];
  __shared__ double part[2][HIDW];
  __shared__ double red4[4];
  __shared__ double lg[NEXP + NMODE];

  // ---- LayerNorm (f64) ----
  double v = (double)phi[b * INDIM + t];
  double s = v;
  #pragma unroll
  for (int off = 32; off; off >>= 1) s += __shfl_down(s, off);
  if ((t & 63) == 0) red4[t >> 6] = s;
  __syncthreads();
  double mu = (red4[0] + red4[1] + red4[2] + red4[3]) * (1.0 / 256.0);
  double dv = v - mu;
  double s2 = dv * dv;
  #pragma unroll
  for (int off = 32; off; off >>= 1) s2 += __shfl_down(s2, off);
  __syncthreads();
  if ((t & 63) == 0) red4[t >> 6] = s2;
  __syncthreads();
  double var = (red4[0] + red4[1] + red4[2] + red4[3]) * (1.0 / 256.0);
  xs[t] = dv * (1.0 / sqrt(var + 1e-5)) * (double)ln_g[t] + (double)ln_b[t];
  __syncthreads();

  const int n = t & 127, h = t >> 7;

  // ---- W1 (256->128): 2 threads per neuron, multi-accumulator ----
  {
    double a0 = 0.0, a1 = 0.0;
    const int i0 = h * 128;
    #pragma unroll 4
    for (int i = 0; i < 128; i += 2) {
      a0 += xs[i0 + i]     * (double)W1[(i0 + i)     * HIDW + n];
      a1 += xs[i0 + i + 1] * (double)W1[(i0 + i + 1) * HIDW + n];
    }
    part[h][n] = a0 + a1;
  }
  __syncthreads();
  if (h == 0) {
    double a = part[0][n] + part[1][n] + (double)b1[n];
    hs[n] = a * 0.5 * (1.0 + erf(a * 0.70710678118654752440));
  }
  __syncthreads();

  // ---- W2 (128->128) ----
  {
    double a0 = 0.0, a1 = 0.0;
    const int i0 = h * 64;
    #pragma unroll 4
    for (int i = 0; i < 64; i += 2) {
      a0 += hs[i0 + i]     * (double)W2[(i0 + i)     * HIDW + n];
      a1 += hs[i0 + i + 1] * (double)W2[(i0 + i + 1) * HIDW + n];
    }
    part[h][n] = a0 + a1;
  }
  __syncthreads();
  double h2v = 0.0;
  if (h == 0) {
    double a = part[0][n] + part[1][n] + (double)b2[n];
    h2v = a * 0.5 * (1.0 + erf(a * 0.70710678118654752440));
  }
  __syncthreads();
  if (h == 0) part[0][n] = h2v;   // reuse part[0] as h2 storage
  __syncthreads();

  // ---- heads: 12 outputs x 128 inputs, 16 lanes per output ----
  if (t < 192) {
    const int g = t >> 4, j = t & 15;
    const float* W; int stride, col; double bias;
    if (g < NEXP) { W = We; stride = NEXP;  col = g;        bias = (double)be[g]; }
    else          { W = Wm; stride = NMODE; col = g - NEXP; bias = (double)bm[g - NEXP]; }
    double a = 0.0;
    #pragma unroll
    for (int i = 0; i < 8; ++i)
      a += part[0][j * 8 + i] * (double)W[(j * 8 + i) * stride + col];
    a += __shfl_down(a, 8);
    a += __shfl_down(a, 4);
    a += __shfl_down(a, 2);
    a += __shfl_down(a, 1);
    if (j == 0) lg[g] = a + bias;
  }
  __syncthreads();
  if (t == 0) {
    int best = 0; double bv = lg[0];
    for (int j = 1; j < NEXP; ++j) if (lg[j] > bv) { bv = lg[j]; best = j; }
    eidx_out[b] = best;
    double m = lg[NEXP];
    for (int j = 1; j < NMODE; ++j) m = fmax(m, lg[NEXP + j]);
    double den = 0.0, num = 0.0;
    for (int j = 0; j < NMODE; ++j) {
      double e = exp(lg[NEXP + j] - m);
      den += e; num += e * (0.25 * (j + 1));
    }
    scale_out[b] = (float)(num / den);
  }
}

// ---- 16-QAM soft demod for one (token, symbol): 4 soft bits -> one constellation point ----
__device__ __forceinline__ void demod_store(const float* __restrict__ sb,
                                            float scale_b, float* __restrict__ op)
{
  float u0 = sb[0], u1 = sb[1], u2 = sb[2], u3 = sb[3];
  float wsum = 0.f, xa = 0.f, ya = 0.f;
  #pragma unroll
  for (int m = 0; m < 16; ++m) {
    float su = 0.f;
    if (m & 8) su += u0;
    if (m & 4) su += u1;
    if (m & 2) su += u2;
    if (m & 1) su += u3;
    const float pc = (float)__builtin_popcount(m);
    float ev = __builtin_amdgcn_exp2f(su * RLN2_4 - pc * RLN2_2);
    wsum += ev;
    xa += ev * (float)(2 * (m >> 2) - 3);
    ya += ev * (float)(2 * (m & 3) - 3);
  }
  const float fac = scale_b * 0.23570226039551584f * __builtin_amdgcn_rcpf(wsum);
  *(float2*)op = make_float2(xa * fac, ya * fac);
}

// ---------------- Fused VQ, transposed MFMA (codes=M, tokens=N) ----
// 64 tokens per wave (4 nt-groups): each LDS (C, a0, a1) triple feeds 8 MFMAs
// -> inner-loop LDS b128 traffic per token halved vs the 2-nt baseline.
//
// SPILL FIX (rounds 1-3 post-mortem): the gfx950 backend splits the wave's
// unified register budget 50/50 arch-VGPR/AGPR when MFMA is present
// (observed: (256,3)->84 arch, (256,4)->64 arch = budget/2, both spilling
// ~70MB of scratch write-back while AGPRs sat idle). Fix: park the 8
// persistent z fragments (32 regs) in AGPRs by issuing the MFMAs as inline
// asm with the B operand under an "a" constraint (gfx950 MFMA reads A/B
// from VGPR or AGPR). Arch-side persistent state drops to ~38 regs -> fits
// the 84-reg arch half with room for window transients.
//   - "=&v" early-clobber on D: must not alias A/B (read during passes).
//   - 2x s_nop 7 after the chained MFMAs: hazard recognizer cannot see
//     inside asm; covers MFMA->VALU-read-of-D wait states.
//   - chained MFMA accumulate (D==C of 2nd) back-to-back is architecturally
//     legal (standard GEMM pattern, m97 asm shows 16 consecutive mfma).
// Codebook pre-scaled by 4/ln2 so MFMA output IS the exp2 argument; no
// max-subtraction (logits bounded ~±9, f32-exact softmax ratio).
// Epilogue: two explicit half-passes (nt 0,1 then 2,3); sb_s stays 4KB with
// wave-synchronous WAR reuse (proven pattern, all rounds passed).
__global__ __launch_bounds__(256, 3)
void vq_kernel(const float* __restrict__ z, const float* __restrict__ codebooks,
               const float* __restrict__ scale_arr, const int* __restrict__ eidx,
               float* __restrict__ out)
{
  __shared__ __align__(16) bf16 cb_s[KC * DC];   // 32768 B, stride 64, 16B-chunk XOR swizzle
  __shared__ float cn2h_s[KC];                   //  1024 B  (-(ln2/8)*sum(cbs^2))
  __shared__ __align__(16) float sb_s[4][32 * 8];//  4096 B  per-wave soft bits (half-pass reuse)

  const int blk  = blockIdx.x;
  const int b    = blk >> 3;
  const int tg   = blk & 7;
  const int tid  = threadIdx.x;
  const int lane = tid & 63;
  const int wid  = tid >> 6;
  const int q    = lane >> 4;
  const int c    = lane & 15;

  // ---- stage codebook: thread = code row, bf16(cb*4/ln2) + chunk swizzle + norm ----
  {
    const int e = eidx[b];
    const float* __restrict__ src = codebooks + (size_t)e * KC * DC + tid * DC;
    char* dstrow = (char*)cb_s + tid * 128;
    const int sw = tid & 7;
    float nrm = 0.f;
    #pragma unroll
    for (int j = 0; j < 8; ++j) {
      float4 va = *(const float4*)(src + j * 8);
      float4 vb = *(const float4*)(src + j * 8 + 4);
      bf16x8 p;
      p[0] = (bf16)(va.x * RLN2_4); p[1] = (bf16)(va.y * RLN2_4);
      p[2] = (bf16)(va.z * RLN2_4); p[3] = (bf16)(va.w * RLN2_4);
      p[4] = (bf16)(vb.x * RLN2_4); p[5] = (bf16)(vb.y * RLN2_4);
      p[6] = (bf16)(vb.z * RLN2_4); p[7] = (bf16)(vb.w * RLN2_4);
      #pragma unroll
      for (int u = 0; u < 8; ++u) { float f = (float)p[u]; nrm += f * f; }
      *(bf16x8*)(dstrow + ((j ^ sw) * 16)) = p;
    }
    cn2h_s[tid] = -NLN2_8 * nrm;
  }
  const float scale_b = scale_arr[b];
  __syncthreads();

  // per-lane LDS A-fragment bases (chunk swizzle folded in)
  const char* pa0 = (const char*)cb_s + c * 128 + ((q    ) ^ (c & 7)) * 16;
  const char* pa1 = (const char*)cb_s + c * 128 + ((q + 4) ^ (c & 7)) * 16;
  const float* __restrict__ cn2q = cn2h_s + q * 4;

  const int tokw = tg * 256 + wid * 64;   // this wave's 64 tokens

  // ---- B fragments for all 4 16-token groups: named scalars ----
  bf16x8 zb00, zb01, zb10, zb11, zb20, zb21, zb30, zb31;
#define LOADZ(NT) do { \
    const float* __restrict__ zt = z + ((size_t)b * NTOK + tokw + (NT) * 16 + c) * DC + q * 8; \
    float4 va = *(const float4*)(zt); \
    float4 vb = *(const float4*)(zt + 4); \
    bf16x8 p; \
    p[0] = (bf16)va.x; p[1] = (bf16)va.y; p[2] = (bf16)va.z; p[3] = (bf16)va.w; \
    p[4] = (bf16)vb.x; p[5] = (bf16)vb.y; p[6] = (bf16)vb.z; p[7] = (bf16)vb.w; \
    zb##NT##0 = p; \
    va = *(const float4*)(zt + 32); \
    vb = *(const float4*)(zt + 36); \
    p[0] = (bf16)va.x; p[1] = (bf16)va.y; p[2] = (bf16)va.z; p[3] = (bf16)va.w; \
    p[4] = (bf16)vb.x; p[5] = (bf16)vb.y; p[6] = (bf16)vb.z; p[7] = (bf16)vb.w; \
    zb##NT##1 = p; \
  } while (0)
  LOADZ(0); LOADZ(1); LOADZ(2); LOADZ(3);
#undef LOADZ

  // ---- accumulators: 28 named floats (E, bit-sums SA..SD, r-sums RA,RB per nt) ----
  float E0 = 0.f, E1 = 0.f, E2 = 0.f, E3 = 0.f;
  float SA0 = 0.f, SA1 = 0.f, SA2 = 0.f, SA3 = 0.f;
  float SB0 = 0.f, SB1 = 0.f, SB2 = 0.f, SB3 = 0.f;
  float SC0 = 0.f, SC1 = 0.f, SC2 = 0.f, SC3 = 0.f;
  float SD0 = 0.f, SD1 = 0.f, SD2 = 0.f, SD3 = 0.f;
  float RA0 = 0.f, RA1 = 0.f, RA2 = 0.f, RA3 = 0.f;
  float RB0 = 0.f, RB1 = 0.f, RB2 = 0.f, RB3 = 0.f;

  // ---- streamed: per code-tile ct, 1 C + 2 A LDS reads feed 8 MFMAs (4 nt) ----
  // code = ct*16 + q*4 + r, token = col c (+ nt*16)
  // label bits (MSB-first): b0..b3 = ct bits 3..0, b4=(q>=2), b5=(q&1), b6=(r>=2), b7=(r&1)
  // D = A*B + C ; A = codebook frag (VGPR, from LDS), B = z frag (AGPR,
  // persistent), C = cinit / chained acc.
#define VQSTEP(NT) do { \
    f32x4 acc; \
    asm("v_mfma_f32_16x16x32_bf16 %0, %2, %3, %1\n\t" \
        "v_mfma_f32_16x16x32_bf16 %0, %4, %5, %0\n\t" \
        "s_nop 7\n\t" \
        "s_nop 7" \
        : "=&v"(acc) \
        : "v"(cinit), "v"(a0f), "a"(zb##NT##0), "v"(a1f), "a"(zb##NT##1)); \
    float e0 = __builtin_amdgcn_exp2f(acc[0]); \
    float e1 = __builtin_amdgcn_exp2f(acc[1]); \
    float e2 = __builtin_amdgcn_exp2f(acc[2]); \
    float e3 = __builtin_amdgcn_exp2f(acc[3]); \
    float s01 = e0 + e1, s23 = e2 + e3, g = s01 + s23; \
    E##NT += g; RA##NT += s23; RB##NT += e1 + e3; \
    if (ct & 8) SA##NT += g; \
    if (ct & 4) SB##NT += g; \
    if (ct & 2) SC##NT += g; \
    if (ct & 1) SD##NT += g; \
  } while (0)

  #pragma unroll
  for (int cc = 0; cc < 8; ++cc) {
    #pragma unroll
    for (int ci = 0; ci < 2; ++ci) {
      const int ct = cc * 2 + ci;
      const f32x4 cinit = *(const f32x4*)(cn2q + ct * 16);
      const bf16x8 a0f = *(const bf16x8*)(pa0 + ct * 2048);
      const bf16x8 a1f = *(const bf16x8*)(pa1 + ct * 2048);
      VQSTEP(0); VQSTEP(1); VQSTEP(2); VQSTEP(3);
    }
    __builtin_amdgcn_sched_barrier(0);   // bound transient-overlap window -> no spills
  }
#undef VQSTEP

  // ---- epilogue: cross-q butterflies + sb write, per nt (explicit, no loop) ----
#define EPIL(NT, NL) do { \
    float En = E##NT; \
    float Ep = En + __shfl_xor(En, 16);  /* q01: E0+E1 ; q23: E2+E3 (bit4 numer at q>=2) */ \
    float B5 = En + __shfl_xor(En, 32);  /* q odd: E1+E3 (bit5 numer) */ \
    float Et = Ep + __shfl_xor(Ep, 32);  /* total */ \
    float s0 = SA##NT, s1 = SB##NT, s2 = SC##NT, s3 = SD##NT; \
    float r0 = RA##NT, r1 = RB##NT; \
    s0 += __shfl_xor(s0, 16); s0 += __shfl_xor(s0, 32); \
    s1 += __shfl_xor(s1, 16); s1 += __shfl_xor(s1, 32); \
    s2 += __shfl_xor(s2, 16); s2 += __shfl_xor(s2, 32); \
    s3 += __shfl_xor(s3, 16); s3 += __shfl_xor(s3, 32); \
    r0 += __shfl_xor(r0, 16); r0 += __shfl_xor(r0, 32); \
    r1 += __shfl_xor(r1, 16); r1 += __shfl_xor(r1, 32); \
    const float rinv = __builtin_amdgcn_rcpf(Et); \
    float* row = &sb_s[wid][((NL) * 16 + c) * 8]; \
    float v1 = (q == 0) ? s0 : (q == 1) ? s1 : (q == 2) ? s2 : s3; \
    float v2 = (q == 0) ? r0 : (q == 1) ? B5 : (q == 2) ? Ep : r1; \
    const int p2 = (q == 3) ? 7 : (6 - q); \
    row[q]  = v1 * rinv; \
    row[p2] = v2 * rinv; \
  } while (0)

  // half-pass 0: nt 0,1 -> tokens tokw..tokw+31
  EPIL(0, 0);
  EPIL(1, 1);
  {
    const int tok = lane >> 1, sym = lane & 1;
    const int nidx = tokw + tok;
    demod_store(&sb_s[wid][tok * 8 + sym * 4], scale_b,
                out + (((size_t)b * NSYM) + 2 * (size_t)nidx + sym) * 2);
  }
  // half-pass 1: nt 2,3 -> tokens tokw+32..tokw+63 (sb_s rows reused, in-wave DS order)
  EPIL(2, 0);
  EPIL(3, 1);
  {
    const int tok = lane >> 1, sym = lane & 1;
    const int nidx = tokw + 32 + tok;
    demod_store(&sb_s[wid][tok * 8 + sym * 4], scale_b,
                out + (((size_t)b * NSYM) + 2 * (size_t)nidx + sym) * 2);
  }
#undef EPIL
}

extern "C" void kernel_launch(void* const* d_in, const int* in_sizes, int n_in,
                              void* d_out, int out_size, void* d_ws, size_t ws_size,
                              hipStream_t stream) {
  const float* phi  = (const float*)d_in[0];
  const float* z    = (const float*)d_in[1];
  const float* ln_g = (const float*)d_in[2];
  const float* ln_b = (const float*)d_in[3];
  const float* W1   = (const float*)d_in[4];
  const float* b1   = (const float*)d_in[5];
  const float* W2   = (const float*)d_in[6];
  const float* b2   = (const float*)d_in[7];
  const float* We   = (const float*)d_in[8];
  const float* be   = (const float*)d_in[9];
  const float* Wm   = (const float*)d_in[10];
  const float* bm   = (const float*)d_in[11];
  const float* cbk  = (const float*)d_in[12];
  float* out   = (float*)d_out;
  float* scale = (float*)d_ws;
  int*   eidx  = (int*)((char*)d_ws + 512);

  router_kernel<<<NB, 256, 0, stream>>>(phi, ln_g, ln_b, W1, b1, W2, b2,
                                        We, be, Wm, bm, scale, eidx);
  vq_kernel<<<NB * 8, 256, 0, stream>>>(z, cbk, scale, eidx, out);
}

// Round 5
// 150.635 us; speedup vs baseline: 1.1693x; 1.1693x over previous
//
#include <hip/hip_runtime.h>

typedef __bf16 bf16;
typedef bf16 bf16x8 __attribute__((ext_vector_type(8)));
typedef float f32x4 __attribute__((ext_vector_type(4)));

#define NB    128
#define NTOK  2048
#define INDIM 256
#define HIDW  128
#define NEXP  8
#define NMODE 4
#define KC    256
#define KH    128      // codes staged per half (16 KB LDS)
#define DC    64
#define NSYM  4096

#define RLN2_4 5.770780163555853f    // 4/ln2
#define RLN2_2 2.8853900817779268f   // 2/ln2
#define NLN2_8 0.0866433975699932f   // ln2/8

// ---------------- Router: LN -> GELU MLP -> expert argmax + power scale (f64, parallel dots) ----
__global__ __launch_bounds__(256)
void router_kernel(const float* __restrict__ phi,
                   const float* __restrict__ ln_g, const float* __restrict__ ln_b,
                   const float* __restrict__ W1, const float* __restrict__ b1,
                   const float* __restrict__ W2, const float* __restrict__ b2,
                   const float* __restrict__ We, const float* __restrict__ be,
                   const float* __restrict__ Wm, const float* __restrict__ bm,
                   float* __restrict__ scale_out, int* __restrict__ eidx_out)
{
  const int b = blockIdx.x, t = threadIdx.x;
  __shared__ double xs[INDIM];
  __shared__ double hs[HIDW];
  __shared__ double part[2][HIDW];
  __shared__ double red4[4];
  __shared__ double lg[NEXP + NMODE];

  // ---- LayerNorm (f64) ----
  double v = (double)phi[b * INDIM + t];
  double s = v;
  #pragma unroll
  for (int off = 32; off; off >>= 1) s += __shfl_down(s, off);
  if ((t & 63) == 0) red4[t >> 6] = s;
  __syncthreads();
  double mu = (red4[0] + red4[1] + red4[2] + red4[3]) * (1.0 / 256.0);
  double dv = v - mu;
  double s2 = dv * dv;
  #pragma unroll
  for (int off = 32; off; off >>= 1) s2 += __shfl_down(s2, off);
  __syncthreads();
  if ((t & 63) == 0) red4[t >> 6] = s2;
  __syncthreads();
  double var = (red4[0] + red4[1] + red4[2] + red4[3]) * (1.0 / 256.0);
  xs[t] = dv * (1.0 / sqrt(var + 1e-5)) * (double)ln_g[t] + (double)ln_b[t];
  __syncthreads();

  const int n = t & 127, h = t >> 7;

  // ---- W1 (256->128): 2 threads per neuron, multi-accumulator ----
  {
    double a0 = 0.0, a1 = 0.0;
    const int i0 = h * 128;
    #pragma unroll 4
    for (int i = 0; i < 128; i += 2) {
      a0 += xs[i0 + i]     * (double)W1[(i0 + i)     * HIDW + n];
      a1 += xs[i0 + i + 1] * (double)W1[(i0 + i + 1) * HIDW + n];
    }
    part[h][n] = a0 + a1;
  }
  __syncthreads();
  if (h == 0) {
    double a = part[0][n] + part[1][n] + (double)b1[n];
    hs[n] = a * 0.5 * (1.0 + erf(a * 0.70710678118654752440));
  }
  __syncthreads();

  // ---- W2 (128->128) ----
  {
    double a0 = 0.0, a1 = 0.0;
    const int i0 = h * 64;
    #pragma unroll 4
    for (int i = 0; i < 64; i += 2) {
      a0 += hs[i0 + i]     * (double)W2[(i0 + i)     * HIDW + n];
      a1 += hs[i0 + i + 1] * (double)W2[(i0 + i + 1) * HIDW + n];
    }
    part[h][n] = a0 + a1;
  }
  __syncthreads();
  double h2v = 0.0;
  if (h == 0) {
    double a = part[0][n] + part[1][n] + (double)b2[n];
    h2v = a * 0.5 * (1.0 + erf(a * 0.70710678118654752440));
  }
  __syncthreads();
  if (h == 0) part[0][n] = h2v;   // reuse part[0] as h2 storage
  __syncthreads();

  // ---- heads: 12 outputs x 128 inputs, 16 lanes per output ----
  if (t < 192) {
    const int g = t >> 4, j = t & 15;
    const float* W; int stride, col; double bias;
    if (g < NEXP) { W = We; stride = NEXP;  col = g;        bias = (double)be[g]; }
    else          { W = Wm; stride = NMODE; col = g - NEXP; bias = (double)bm[g - NEXP]; }
    double a = 0.0;
    #pragma unroll
    for (int i = 0; i < 8; ++i)
      a += part[0][j * 8 + i] * (double)W[(j * 8 + i) * stride + col];
    a += __shfl_down(a, 8);
    a += __shfl_down(a, 4);
    a += __shfl_down(a, 2);
    a += __shfl_down(a, 1);
    if (j == 0) lg[g] = a + bias;
  }
  __syncthreads();
  if (t == 0) {
    int best = 0; double bv = lg[0];
    for (int j = 1; j < NEXP; ++j) if (lg[j] > bv) { bv = lg[j]; best = j; }
    eidx_out[b] = best;
    double m = lg[NEXP];
    for (int j = 1; j < NMODE; ++j) m = fmax(m, lg[NEXP + j]);
    double den = 0.0, num = 0.0;
    for (int j = 0; j < NMODE; ++j) {
      double e = exp(lg[NEXP + j] - m);
      den += e; num += e * (0.25 * (j + 1));
    }
    scale_out[b] = (float)(num / den);
  }
}

// ---- stage one 128-code half of the codebook: 2 threads per code row ----
// bf16(cb*4/ln2), 16B-chunk XOR swizzle (sw = code&7), norm via lane-pair shuffle.
__device__ __forceinline__ void stage_half(int half, int tid, int e,
                                           const float* __restrict__ codebooks,
                                           bf16* cb_s, float* cn2h_s)
{
  const int code = tid >> 1, prt = tid & 1;
  const float* __restrict__ src = codebooks + (size_t)e * KC * DC
                                + (size_t)(half * KH + code) * DC + prt * 32;
  char* dstrow = (char*)cb_s + code * 128;
  const int sw = code & 7;
  float nrm = 0.f;
  #pragma unroll
  for (int j2 = 0; j2 < 4; ++j2) {
    const int j = prt * 4 + j2;
    float4 va = *(const float4*)(src + j2 * 8);
    float4 vb = *(const float4*)(src + j2 * 8 + 4);
    bf16x8 p;
    p[0] = (bf16)(va.x * RLN2_4); p[1] = (bf16)(va.y * RLN2_4);
    p[2] = (bf16)(va.z * RLN2_4); p[3] = (bf16)(va.w * RLN2_4);
    p[4] = (bf16)(vb.x * RLN2_4); p[5] = (bf16)(vb.y * RLN2_4);
    p[6] = (bf16)(vb.z * RLN2_4); p[7] = (bf16)(vb.w * RLN2_4);
    #pragma unroll
    for (int u = 0; u < 8; ++u) { float f = (float)p[u]; nrm += f * f; }
    *(bf16x8*)(dstrow + ((j ^ sw) * 16)) = p;
  }
  nrm += __shfl_xor(nrm, 1);            // combine the two 32-dim partials
  if (prt == 0) cn2h_s[code] = -NLN2_8 * nrm;
}

// ---------------- Fused VQ, transposed MFMA (codes=M, tokens=N) ----
// ROUND-5 DIRECTION CHANGE: rounds 1-4 (64-token/wave ILP variants) all
// spilled (~70-90MB scratch write-back) — abandoned per pre-committed
// falsifier. Re-derived pipe model: every pipe (VALU/LDS/trans/MFMA/HBM)
// is <=26% of the baseline's 39us -> the kernel is LATENCY-bound, and
// occupancy is capped at 4 waves/SIMD by the 37.9KB LDS block (cb_s 32KB).
// Fix TLP instead of ILP: stage the codebook in TWO 128-code halves
// (16KB each) -> LDS 20.5KB -> 6 blocks/CU (VGPR-84-capped), +50% waves.
// Inner 2-nt sweep, accumulator arrays, 4-ct sched_barrier windows, and
// epilogue are VERBATIM round-0 (proven spill-free at 141us). Bit-0 of the
// code label (ct&8) == the half index -> S0 accumulates unconditionally in
// the half-1 sweep only; other bit gates are local. Global ct traversal
// order (0..15 ascending) and therefore summation order is bit-identical
// to round 0.
__global__ __launch_bounds__(256, 3)
void vq_kernel(const float* __restrict__ z, const float* __restrict__ codebooks,
               const float* __restrict__ scale_arr, const int* __restrict__ eidx,
               float* __restrict__ out)
{
  __shared__ __align__(16) bf16 cb_s[KH * DC];   // 16384 B, stride 64, 16B-chunk XOR swizzle
  __shared__ float cn2h_s[KH];                   //   512 B  (-(ln2/8)*sum(cbs^2))
  __shared__ __align__(16) float sb_s[4][32 * 8];//  4096 B  per-wave soft bits

  const int blk  = blockIdx.x;
  const int b    = blk >> 4;       // 16 blocks per batch item
  const int tg   = blk & 15;
  const int tid  = threadIdx.x;
  const int lane = tid & 63;
  const int wid  = tid >> 6;
  const int q    = lane >> 4;
  const int c    = lane & 15;

  const int e = eidx[b];
  const float scale_b = scale_arr[b];

  // ---- stage first half (codes 0..127) ----
  stage_half(0, tid, e, codebooks, cb_s, cn2h_s);
  __syncthreads();

  // per-lane LDS A-fragment bases (chunk swizzle folded in)
  const char* pa0 = (const char*)cb_s + c * 128 + ((q    ) ^ (c & 7)) * 16;
  const char* pa1 = (const char*)cb_s + c * 128 + ((q + 4) ^ (c & 7)) * 16;
  const float* __restrict__ cn2q = cn2h_s + q * 4;

  const int tokw = tg * 128 + wid * 32;   // this wave's 32 tokens

  // ---- B fragments for both 16-token groups: z direct from global (f32 -> bf16) ----
  bf16x8 zb[2][2];   // [nt][ks]
  #pragma unroll
  for (int nt = 0; nt < 2; ++nt) {
    const float* __restrict__ zt = z + ((size_t)b * NTOK + tokw + nt * 16 + c) * DC + q * 8;
    #pragma unroll
    for (int ks = 0; ks < 2; ++ks) {
      float4 va = *(const float4*)(zt + ks * 32);
      float4 vb = *(const float4*)(zt + ks * 32 + 4);
      bf16x8 p;
      p[0] = (bf16)va.x; p[1] = (bf16)va.y; p[2] = (bf16)va.z; p[3] = (bf16)va.w;
      p[4] = (bf16)vb.x; p[5] = (bf16)vb.y; p[6] = (bf16)vb.z; p[7] = (bf16)vb.w;
      zb[nt][ks] = p;
    }
  }

  // ---- accumulators (round-0 layout): E, bit-sums S0..S3, r-sums R0,R1 per nt ----
  float E[2]  = {0.f, 0.f}, S0[2] = {0.f, 0.f}, S1[2] = {0.f, 0.f},
        S2[2] = {0.f, 0.f}, S3[2] = {0.f, 0.f}, R0[2] = {0.f, 0.f}, R1[2] = {0.f, 0.f};

  // ---- streamed sweep over one staged half: per code-tile ct (local 0..7),
  // 1 C + 2 A LDS reads feed 4 MFMAs (2 nt).
  // local code = ct*16 + q*4 + r; global code adds half*128.
  // label bits (MSB-first): b0=half, b1..b3 = local ct bits 2..0,
  // b4=(q>=2), b5=(q&1), b6=(r>=2), b7=(r&1)
#define SWEEP(HALFBIT) \
  _Pragma("unroll") \
  for (int cc = 0; cc < 2; ++cc) { \
    _Pragma("unroll") \
    for (int ci = 0; ci < 4; ++ci) { \
      const int ct = cc * 4 + ci; \
      f32x4 cinit = *(const f32x4*)(cn2q + ct * 16); \
      bf16x8 a0 = *(const bf16x8*)(pa0 + ct * 2048); \
      bf16x8 a1 = *(const bf16x8*)(pa1 + ct * 2048); \
      _Pragma("unroll") \
      for (int nt = 0; nt < 2; ++nt) { \
        f32x4 a = __builtin_amdgcn_mfma_f32_16x16x32_bf16(a0, zb[nt][0], cinit, 0, 0, 0); \
        a = __builtin_amdgcn_mfma_f32_16x16x32_bf16(a1, zb[nt][1], a, 0, 0, 0); \
        float e0 = __builtin_amdgcn_exp2f(a[0]); \
        float e1 = __builtin_amdgcn_exp2f(a[1]); \
        float e2 = __builtin_amdgcn_exp2f(a[2]); \
        float e3 = __builtin_amdgcn_exp2f(a[3]); \
        float s01 = e0 + e1, s23 = e2 + e3, g = s01 + s23; \
        E[nt] += g; R0[nt] += s23; R1[nt] += e1 + e3; \
        if (HALFBIT) S0[nt] += g; \
        if (ct & 4) S1[nt] += g; \
        if (ct & 2) S2[nt] += g; \
        if (ct & 1) S3[nt] += g; \
      } \
    } \
    __builtin_amdgcn_sched_barrier(0); /* bound load-hoisting window -> no spills */ \
  }

  SWEEP(0)

  // ---- swap in second half (codes 128..255); accumulators persist ----
  __syncthreads();                       // all waves done reading half 0
  stage_half(1, tid, e, codebooks, cb_s, cn2h_s);
  __syncthreads();

  SWEEP(1)
#undef SWEEP

  // ---- cross-q combine: 2-stage butterflies, bit4/bit5 from E intermediates ----
  #pragma unroll
  for (int nt = 0; nt < 2; ++nt) {
    float En = E[nt];
    float Ep = En + __shfl_xor(En, 16);      // q01: E0+E1 ; q23: E2+E3 (= bit4 numer at q>=2)
    float B5 = En + __shfl_xor(En, 32);      // q odd: E1+E3 (= bit5 numer)
    float Et = Ep + __shfl_xor(Ep, 32);      // total
    float s0 = S0[nt], s1 = S1[nt], s2 = S2[nt], s3 = S3[nt], r0 = R0[nt], r1 = R1[nt];
    #define BF2(x) x += __shfl_xor(x, 16); x += __shfl_xor(x, 32);
    BF2(s0) BF2(s1) BF2(s2) BF2(s3) BF2(r0) BF2(r1)
    #undef BF2
    const float rinv = __builtin_amdgcn_rcpf(Et);

    float* row = &sb_s[wid][(nt * 16 + c) * 8];
    float v1 = (q == 0) ? s0 : (q == 1) ? s1 : (q == 2) ? s2 : s3;
    float v2 = (q == 0) ? r0 : (q == 1) ? B5 : (q == 2) ? Ep : r1;
    const int p2 = (q == 3) ? 7 : (6 - q);
    row[q]  = v1 * rinv;
    row[p2] = v2 * rinv;
  }

  // ---- 16-QAM soft demod: lane = (token, symbol), 32 tokens x 2 syms ----
  {
    const int tok = lane >> 1, sym = lane & 1;
    const float* sb = &sb_s[wid][tok * 8 + sym * 4];
    float u0 = sb[0], u1 = sb[1], u2 = sb[2], u3 = sb[3];
    float wsum = 0.f, xa = 0.f, ya = 0.f;
    #pragma unroll
    for (int m = 0; m < 16; ++m) {
      float su = 0.f;
      if (m & 8) su += u0;
      if (m & 4) su += u1;
      if (m & 2) su += u2;
      if (m & 1) su += u3;
      const float pc = (float)__builtin_popcount(m);
      float ev = __builtin_amdgcn_exp2f(su * RLN2_4 - pc * RLN2_2);
      wsum += ev;
      xa += ev * (float)(2 * (m >> 2) - 3);
      ya += ev * (float)(2 * (m & 3) - 3);
    }
    const float fac = scale_b * 0.23570226039551584f * __builtin_amdgcn_rcpf(wsum);
    const int nidx = tokw + tok;
    float2* op = (float2*)(out + (((size_t)b * NSYM) + 2 * (size_t)nidx + sym) * 2);
    *op = make_float2(xa * fac, ya * fac);
  }
}

extern "C" void kernel_launch(void* const* d_in, const int* in_sizes, int n_in,
                              void* d_out, int out_size, void* d_ws, size_t ws_size,
                              hipStream_t stream) {
  const float* phi  = (const float*)d_in[0];
  const float* z    = (const float*)d_in[1];
  const float* ln_g = (const float*)d_in[2];
  const float* ln_b = (const float*)d_in[3];
  const float* W1   = (const float*)d_in[4];
  const float* b1   = (const float*)d_in[5];
  const float* W2   = (const float*)d_in[6];
  const float* b2   = (const float*)d_in[7];
  const float* We   = (const float*)d_in[8];
  const float* be   = (const float*)d_in[9];
  const float* Wm   = (const float*)d_in[10];
  const float* bm   = (const float*)d_in[11];
  const float* cbk  = (const float*)d_in[12];
  float* out   = (float*)d_out;
  float* scale = (float*)d_ws;
  int*   eidx  = (int*)((char*)d_ws + 512);

  router_kernel<<<NB, 256, 0, stream>>>(phi, ln_g, ln_b, W1, b1, W2, b2,
                                        We, be, Wm, bm, scale, eidx);
  vq_kernel<<<NB * 16, 256, 0, stream>>>(z, cbk, scale, eidx, out);
}

// Round 6
// 138.069 us; speedup vs baseline: 1.2757x; 1.0910x over previous
//
#include <hip/hip_runtime.h>

typedef __bf16 bf16;
typedef bf16 bf16x8 __attribute__((ext_vector_type(8)));
typedef float f32x4 __attribute__((ext_vector_type(4)));

#define NB    128
#define NTOK  2048
#define INDIM 256
#define HIDW  128
#define NEXP  8
#define NMODE 4
#define KC    256
#define KH    128      // codes staged per half (16 KB LDS)
#define DC    64
#define NSYM  4096

#define RLN2_4 5.770780163555853f    // 4/ln2
#define RLN2_2 2.8853900817779268f   // 2/ln2
#define NLN2_8 0.0866433975699932f   // ln2/8

// ---------------- Fused Router + codebook prep ----------------
// Blocks 0..NB-1: router (LN -> GELU MLP -> expert argmax + power scale, f64).
// Blocks NB..NB+7: convert all 8 experts' codebooks to bf16(cb*4/ln2) + norms
// into the workspace — ONCE, instead of per-vq-block (rounds 0-5 redundantly
// re-converted the same 512KB in every one of 1024-2048 blocks ≈ 8-9us of
// chip-wide VALU). Prep math/order is IDENTICAL to the old in-kernel staging
// (same cvt, same f32 accumulation order) -> bit-identical vq numerics.
__global__ __launch_bounds__(256)
void router_prep_kernel(const float* __restrict__ phi,
                        const float* __restrict__ ln_g, const float* __restrict__ ln_b,
                        const float* __restrict__ W1, const float* __restrict__ b1,
                        const float* __restrict__ W2, const float* __restrict__ b2,
                        const float* __restrict__ We, const float* __restrict__ be,
                        const float* __restrict__ Wm, const float* __restrict__ bm,
                        const float* __restrict__ codebooks,
                        float* __restrict__ scale_out, int* __restrict__ eidx_out,
                        bf16* __restrict__ cbB, float* __restrict__ cn2B)
{
  if (blockIdx.x >= NB) {
    // ---- codebook prep: one thread per code row (8 blocks x 256 thr = 2048 rows) ----
    const int r = (blockIdx.x - NB) * 256 + threadIdx.x;
    const float* __restrict__ src = codebooks + (size_t)r * DC;
    bf16* __restrict__ drow = cbB + (size_t)r * DC;
    float nrm = 0.f;
    #pragma unroll
    for (int j = 0; j < 8; ++j) {
      float4 va = *(const float4*)(src + j * 8);
      float4 vb = *(const float4*)(src + j * 8 + 4);
      bf16x8 p;
      p[0] = (bf16)(va.x * RLN2_4); p[1] = (bf16)(va.y * RLN2_4);
      p[2] = (bf16)(va.z * RLN2_4); p[3] = (bf16)(va.w * RLN2_4);
      p[4] = (bf16)(vb.x * RLN2_4); p[5] = (bf16)(vb.y * RLN2_4);
      p[6] = (bf16)(vb.z * RLN2_4); p[7] = (bf16)(vb.w * RLN2_4);
      #pragma unroll
      for (int u = 0; u < 8; ++u) { float f = (float)p[u]; nrm += f * f; }
      *(bf16x8*)(drow + j * 8) = p;    // LINEAR store; swizzle applied at LDS-stage time
    }
    cn2B[r] = -NLN2_8 * nrm;
    return;
  }

  const int b = blockIdx.x, t = threadIdx.x;
  __shared__ double xs[INDIM];
  __shared__ double hs[HIDW];
  __shared__ double part[2][HIDW];
  __shared__ double red4[4];
  __shared__ double lg[NEXP + NMODE];

  // ---- LayerNorm (f64) ----
  double v = (double)phi[b * INDIM + t];
  double s = v;
  #pragma unroll
  for (int off = 32; off; off >>= 1) s += __shfl_down(s, off);
  if ((t & 63) == 0) red4[t >> 6] = s;
  __syncthreads();
  double mu = (red4[0] + red4[1] + red4[2] + red4[3]) * (1.0 / 256.0);
  double dv = v - mu;
  double s2 = dv * dv;
  #pragma unroll
  for (int off = 32; off; off >>= 1) s2 += __shfl_down(s2, off);
  __syncthreads();
  if ((t & 63) == 0) red4[t >> 6] = s2;
  __syncthreads();
  double var = (red4[0] + red4[1] + red4[2] + red4[3]) * (1.0 / 256.0);
  xs[t] = dv * (1.0 / sqrt(var + 1e-5)) * (double)ln_g[t] + (double)ln_b[t];
  __syncthreads();

  const int n = t & 127, h = t >> 7;

  // ---- W1 (256->128): 2 threads per neuron, multi-accumulator ----
  {
    double a0 = 0.0, a1 = 0.0;
    const int i0 = h * 128;
    #pragma unroll 4
    for (int i = 0; i < 128; i += 2) {
      a0 += xs[i0 + i]     * (double)W1[(i0 + i)     * HIDW + n];
      a1 += xs[i0 + i + 1] * (double)W1[(i0 + i + 1) * HIDW + n];
    }
    part[h][n] = a0 + a1;
  }
  __syncthreads();
  if (h == 0) {
    double a = part[0][n] + part[1][n] + (double)b1[n];
    hs[n] = a * 0.5 * (1.0 + erf(a * 0.70710678118654752440));
  }
  __syncthreads();

  // ---- W2 (128->128) ----
  {
    double a0 = 0.0, a1 = 0.0;
    const int i0 = h * 64;
    #pragma unroll 4
    for (int i = 0; i < 64; i += 2) {
      a0 += hs[i0 + i]     * (double)W2[(i0 + i)     * HIDW + n];
      a1 += hs[i0 + i + 1] * (double)W2[(i0 + i + 1) * HIDW + n];
    }
    part[h][n] = a0 + a1;
  }
  __syncthreads();
  double h2v = 0.0;
  if (h == 0) {
    double a = part[0][n] + part[1][n] + (double)b2[n];
    h2v = a * 0.5 * (1.0 + erf(a * 0.70710678118654752440));
  }
  __syncthreads();
  if (h == 0) part[0][n] = h2v;   // reuse part[0] as h2 storage
  __syncthreads();

  // ---- heads: 12 outputs x 128 inputs, 16 lanes per output ----
  if (t < 192) {
    const int g = t >> 4, j = t & 15;
    const float* W; int stride, col; double bias;
    if (g < NEXP) { W = We; stride = NEXP;  col = g;        bias = (double)be[g]; }
    else          { W = Wm; stride = NMODE; col = g - NEXP; bias = (double)bm[g - NEXP]; }
    double a = 0.0;
    #pragma unroll
    for (int i = 0; i < 8; ++i)
      a += part[0][j * 8 + i] * (double)W[(j * 8 + i) * stride + col];
    a += __shfl_down(a, 8);
    a += __shfl_down(a, 4);
    a += __shfl_down(a, 2);
    a += __shfl_down(a, 1);
    if (j == 0) lg[g] = a + bias;
  }
  __syncthreads();
  if (t == 0) {
    int best = 0; double bv = lg[0];
    for (int j = 1; j < NEXP; ++j) if (lg[j] > bv) { bv = lg[j]; best = j; }
    eidx_out[b] = best;
    double m = lg[NEXP];
    for (int j = 1; j < NMODE; ++j) m = fmax(m, lg[NEXP + j]);
    double den = 0.0, num = 0.0;
    for (int j = 0; j < NMODE; ++j) {
      double e = exp(lg[NEXP + j] - m);
      den += e; num += e * (0.25 * (j + 1));
    }
    scale_out[b] = (float)(num / den);
  }
}

// ---- stage one 128-code half from the PREPPED bf16 codebook: pure copy ----
// 2 threads per code row, 4x b128 load + 4x b128 swizzled LDS write each
// (~10 inst vs ~250 for the old cvt+norm staging). Same cb_s layout as
// rounds 0-5: stride 64 bf16, 16B-chunk XOR swizzle (sw = code&7).
__device__ __forceinline__ void stage_half_pre(int half, int tid, int e,
                                               const bf16* __restrict__ cbB,
                                               const float* __restrict__ cn2B,
                                               bf16* cb_s, float* cn2h_s)
{
  const int code = tid >> 1, prt = tid & 1;
  const bf16* __restrict__ src = cbB + ((size_t)e * KC + half * KH + code) * DC + prt * 32;
  char* dstrow = (char*)cb_s + code * 128;
  const int sw = code & 7;
  #pragma unroll
  for (int j2 = 0; j2 < 4; ++j2) {
    const int j = prt * 4 + j2;
    bf16x8 p = *(const bf16x8*)(src + j2 * 8);
    *(bf16x8*)(dstrow + ((j ^ sw) * 16)) = p;
  }
  if (tid < KH) cn2h_s[tid] = cn2B[e * KC + half * KH + tid];
}

// ---------------- Fused VQ, transposed MFMA (codes=M, tokens=N) ----
// Round-5 structure (two 16KB codebook halves -> 21KB LDS -> 6 blocks/CU)
// with the staging cost removed via the prep kernel. Inner 2-nt sweep,
// accumulators, sched_barrier windows, epilogue: verbatim round 5 (proven
// numerics + no spill at VGPR 84). Global ct traversal order 0..15
// ascending -> summation order bit-identical to rounds 0/5.
__global__ __launch_bounds__(256, 3)
void vq_kernel(const float* __restrict__ z,
               const bf16* __restrict__ cbB, const float* __restrict__ cn2B,
               const float* __restrict__ scale_arr, const int* __restrict__ eidx,
               float* __restrict__ out)
{
  __shared__ __align__(16) bf16 cb_s[KH * DC];   // 16384 B, stride 64, 16B-chunk XOR swizzle
  __shared__ float cn2h_s[KH];                   //   512 B  (-(ln2/8)*sum(cbs^2))
  __shared__ __align__(16) float sb_s[4][32 * 8];//  4096 B  per-wave soft bits

  const int blk  = blockIdx.x;
  const int b    = blk >> 4;       // 16 blocks per batch item
  const int tg   = blk & 15;
  const int tid  = threadIdx.x;
  const int lane = tid & 63;
  const int wid  = tid >> 6;
  const int q    = lane >> 4;
  const int c    = lane & 15;

  const int e = eidx[b];
  const float scale_b = scale_arr[b];

  // ---- stage first half (codes 0..127): pure copy from prepped bf16 ----
  stage_half_pre(0, tid, e, cbB, cn2B, cb_s, cn2h_s);
  __syncthreads();

  // per-lane LDS A-fragment bases (chunk swizzle folded in)
  const char* pa0 = (const char*)cb_s + c * 128 + ((q    ) ^ (c & 7)) * 16;
  const char* pa1 = (const char*)cb_s + c * 128 + ((q + 4) ^ (c & 7)) * 16;
  const float* __restrict__ cn2q = cn2h_s + q * 4;

  const int tokw = tg * 128 + wid * 32;   // this wave's 32 tokens

  // ---- B fragments for both 16-token groups: z direct from global (f32 -> bf16) ----
  bf16x8 zb[2][2];   // [nt][ks]
  #pragma unroll
  for (int nt = 0; nt < 2; ++nt) {
    const float* __restrict__ zt = z + ((size_t)b * NTOK + tokw + nt * 16 + c) * DC + q * 8;
    #pragma unroll
    for (int ks = 0; ks < 2; ++ks) {
      float4 va = *(const float4*)(zt + ks * 32);
      float4 vb = *(const float4*)(zt + ks * 32 + 4);
      bf16x8 p;
      p[0] = (bf16)va.x; p[1] = (bf16)va.y; p[2] = (bf16)va.z; p[3] = (bf16)va.w;
      p[4] = (bf16)vb.x; p[5] = (bf16)vb.y; p[6] = (bf16)vb.z; p[7] = (bf16)vb.w;
      zb[nt][ks] = p;
    }
  }

  // ---- accumulators (round-0 layout): E, bit-sums S0..S3, r-sums R0,R1 per nt ----
  float E[2]  = {0.f, 0.f}, S0[2] = {0.f, 0.f}, S1[2] = {0.f, 0.f},
        S2[2] = {0.f, 0.f}, S3[2] = {0.f, 0.f}, R0[2] = {0.f, 0.f}, R1[2] = {0.f, 0.f};

  // ---- streamed sweep over one staged half: per code-tile ct (local 0..7),
  // 1 C + 2 A LDS reads feed 4 MFMAs (2 nt).
  // local code = ct*16 + q*4 + r; global code adds half*128.
  // label bits (MSB-first): b0=half, b1..b3 = local ct bits 2..0,
  // b4=(q>=2), b5=(q&1), b6=(r>=2), b7=(r&1)
#define SWEEP(HALFBIT) \
  _Pragma("unroll") \
  for (int cc = 0; cc < 2; ++cc) { \
    _Pragma("unroll") \
    for (int ci = 0; ci < 4; ++ci) { \
      const int ct = cc * 4 + ci; \
      f32x4 cinit = *(const f32x4*)(cn2q + ct * 16); \
      bf16x8 a0 = *(const bf16x8*)(pa0 + ct * 2048); \
      bf16x8 a1 = *(const bf16x8*)(pa1 + ct * 2048); \
      _Pragma("unroll") \
      for (int nt = 0; nt < 2; ++nt) { \
        f32x4 a = __builtin_amdgcn_mfma_f32_16x16x32_bf16(a0, zb[nt][0], cinit, 0, 0, 0); \
        a = __builtin_amdgcn_mfma_f32_16x16x32_bf16(a1, zb[nt][1], a, 0, 0, 0); \
        float e0 = __builtin_amdgcn_exp2f(a[0]); \
        float e1 = __builtin_amdgcn_exp2f(a[1]); \
        float e2 = __builtin_amdgcn_exp2f(a[2]); \
        float e3 = __builtin_amdgcn_exp2f(a[3]); \
        float s01 = e0 + e1, s23 = e2 + e3, g = s01 + s23; \
        E[nt] += g; R0[nt] += s23; R1[nt] += e1 + e3; \
        if (HALFBIT) S0[nt] += g; \
        if (ct & 4) S1[nt] += g; \
        if (ct & 2) S2[nt] += g; \
        if (ct & 1) S3[nt] += g; \
      } \
    } \
    __builtin_amdgcn_sched_barrier(0); /* bound load-hoisting window -> no spills */ \
  }

  SWEEP(0)

  // ---- swap in second half (codes 128..255); accumulators persist ----
  __syncthreads();                       // all waves done reading half 0
  stage_half_pre(1, tid, e, cbB, cn2B, cb_s, cn2h_s);
  __syncthreads();

  SWEEP(1)
#undef SWEEP

  // ---- cross-q combine: 2-stage butterflies, bit4/bit5 from E intermediates ----
  #pragma unroll
  for (int nt = 0; nt < 2; ++nt) {
    float En = E[nt];
    float Ep = En + __shfl_xor(En, 16);      // q01: E0+E1 ; q23: E2+E3 (= bit4 numer at q>=2)
    float B5 = En + __shfl_xor(En, 32);      // q odd: E1+E3 (= bit5 numer)
    float Et = Ep + __shfl_xor(Ep, 32);      // total
    float s0 = S0[nt], s1 = S1[nt], s2 = S2[nt], s3 = S3[nt], r0 = R0[nt], r1 = R1[nt];
    #define BF2(x) x += __shfl_xor(x, 16); x += __shfl_xor(x, 32);
    BF2(s0) BF2(s1) BF2(s2) BF2(s3) BF2(r0) BF2(r1)
    #undef BF2
    const float rinv = __builtin_amdgcn_rcpf(Et);

    float* row = &sb_s[wid][(nt * 16 + c) * 8];
    float v1 = (q == 0) ? s0 : (q == 1) ? s1 : (q == 2) ? s2 : s3;
    float v2 = (q == 0) ? r0 : (q == 1) ? B5 : (q == 2) ? Ep : r1;
    const int p2 = (q == 3) ? 7 : (6 - q);
    row[q]  = v1 * rinv;
    row[p2] = v2 * rinv;
  }

  // ---- 16-QAM soft demod: lane = (token, symbol), 32 tokens x 2 syms ----
  {
    const int tok = lane >> 1, sym = lane & 1;
    const float* sb = &sb_s[wid][tok * 8 + sym * 4];
    float u0 = sb[0], u1 = sb[1], u2 = sb[2], u3 = sb[3];
    float wsum = 0.f, xa = 0.f, ya = 0.f;
    #pragma unroll
    for (int m = 0; m < 16; ++m) {
      float su = 0.f;
      if (m & 8) su += u0;
      if (m & 4) su += u1;
      if (m & 2) su += u2;
      if (m & 1) su += u3;
      const float pc = (float)__builtin_popcount(m);
      float ev = __builtin_amdgcn_exp2f(su * RLN2_4 - pc * RLN2_2);
      wsum += ev;
      xa += ev * (float)(2 * (m >> 2) - 3);
      ya += ev * (float)(2 * (m & 3) - 3);
    }
    const float fac = scale_b * 0.23570226039551584f * __builtin_amdgcn_rcpf(wsum);
    const int nidx = tokw + tok;
    float2* op = (float2*)(out + (((size_t)b * NSYM) + 2 * (size_t)nidx + sym) * 2);
    *op = make_float2(xa * fac, ya * fac);
  }
}

extern "C" void kernel_launch(void* const* d_in, const int* in_sizes, int n_in,
                              void* d_out, int out_size, void* d_ws, size_t ws_size,
                              hipStream_t stream) {
  const float* phi  = (const float*)d_in[0];
  const float* z    = (const float*)d_in[1];
  const float* ln_g = (const float*)d_in[2];
  const float* ln_b = (const float*)d_in[3];
  const float* W1   = (const float*)d_in[4];
  const float* b1   = (const float*)d_in[5];
  const float* W2   = (const float*)d_in[6];
  const float* b2   = (const float*)d_in[7];
  const float* We   = (const float*)d_in[8];
  const float* be   = (const float*)d_in[9];
  const float* Wm   = (const float*)d_in[10];
  const float* bm   = (const float*)d_in[11];
  const float* cbk  = (const float*)d_in[12];
  float* out   = (float*)d_out;
  // workspace layout: scale@0 (512B), eidx@512 (512B), cn2@1024 (8KB),
  // cbB@16384 (256KB) -> requires ws_size >= 272KB.
  float* scale = (float*)d_ws;
  int*   eidx  = (int*)((char*)d_ws + 512);
  float* cn2B  = (float*)((char*)d_ws + 1024);
  bf16*  cbB   = (bf16*)((char*)d_ws + 16384);

  router_prep_kernel<<<NB + 8, 256, 0, stream>>>(phi, ln_g, ln_b, W1, b1, W2, b2,
                                                 We, be, Wm, bm, cbk,
                                                 scale, eidx, cbB, cn2B);
  vq_kernel<<<NB * 16, 256, 0, stream>>>(z, cbB, cn2B, scale, eidx, out);
}